// Round 14
// baseline (164.264 us; speedup 1.0000x reference)
//
#include <hip/hip_runtime.h>

#define N_NODES 10000
#define N_EDGES 160000
#define FNODE 8
#define C 24
#define HID 16
#define NB_HEAD 240
#define TW (5 * C)   // 120: per-node T row = [f=0..3 ea-weighted][f=4 bias part]
#define LNPB 16      // nodes per layer block; 625*16 == 10000 exactly

// Module-owned scratch (immune to d_ws poisoning). Fully rebuilt every call.
__device__ float  g_TA[N_NODES * TW];
__device__ float  g_TB[N_NODES * TW];
__device__ float  g_hA[N_NODES * C];
__device__ float  g_hB[N_NODES * C];
__device__ int    g_deg[N_NODES];        // zeroed each call, then hist, then cursor
__device__ int    g_off[N_NODES + 1];
__device__ int    g_csr_src[N_EDGES];    // premultiplied: src * TW
__device__ int    g_csr_dst[N_EDGES];
__device__ float4 g_csr_ea[N_EDGES];
__device__ float  g_partial[NB_HEAD * HID];

// Monotone float <-> uint mapping: unsigned max == float max. fenc(finite)>0,
// so 0u is a safe "no edges" sentinel.
__device__ __forceinline__ unsigned fenc(float f) {
    unsigned u = __float_as_uint(f);
    return (u & 0x80000000u) ? ~u : (u | 0x80000000u);
}
__device__ __forceinline__ float fdec(unsigned u) {
    unsigned v = (u & 0x80000000u) ? (u & 0x7FFFFFFFu) : ~u;
    return __uint_as_float(v);
}

// ---------- CSR build (no device-scope fences anywhere) ----------
__global__ void csr_zero_kernel() {
    const int n = blockIdx.x * blockDim.x + threadIdx.x;
    if (n < N_NODES) g_deg[n] = 0;
}
__global__ void csr_hist_kernel(const int* __restrict__ dst) {
    const int e = blockIdx.x * blockDim.x + threadIdx.x;   // 625*256 exact
    atomicAdd(&g_deg[dst[e]], 1);
}
#define SCAN_T 1024
#define SCAN_I 10
__global__ void csr_scan_kernel() {
    __shared__ int s[SCAN_T];
    const int tid = threadIdx.x;
    const int base = tid * SCAN_I;
    int v[SCAN_I];
    int tot = 0;
#pragma unroll
    for (int j = 0; j < SCAN_I; ++j) {
        const int idx = base + j;
        v[j] = (idx < N_NODES) ? g_deg[idx] : 0;
        tot += v[j];
    }
    s[tid] = tot;
    __syncthreads();
    for (int off = 1; off < SCAN_T; off <<= 1) {
        const int t = (tid >= off) ? s[tid - off] : 0;
        __syncthreads();
        s[tid] += t;
        __syncthreads();
    }
    int run = s[tid] - tot;
#pragma unroll
    for (int j = 0; j < SCAN_I; ++j) {
        const int idx = base + j;
        if (idx < N_NODES) { g_off[idx] = run; g_deg[idx] = run; }  // deg -> cursor
        run += v[j];
    }
    if (tid == 0) g_off[N_NODES] = N_EDGES;
}
__global__ void csr_scatter_kernel(const int* __restrict__ src,
                                   const int* __restrict__ dst,
                                   const float* __restrict__ ea) {
    const int e = blockIdx.x * blockDim.x + threadIdx.x;   // 625*256 exact
    const int d = dst[e];
    const int p = atomicAdd(&g_deg[d], 1);
    g_csr_src[p] = src[e] * TW;
    g_csr_dst[p] = d;
    g_csr_ea[p] = ((const float4*)ea)[e];
}

// ---------- T projection for layer 0 (from x) ----------
template <int IN_C, int TNPB>
__global__ void tmat_kernel(const float* __restrict__ h,
                            const float* __restrict__ W,
                            const float* __restrict__ b,
                            float* __restrict__ T) {
    __shared__ float sW_t[IN_C * TW];
    __shared__ float sh[TNPB][IN_C];
    const int tid = threadIdx.x + threadIdx.y * TW;
    const int nthr = TW * TNPB;
    for (int idx = tid; idx < IN_C * TW; idx += nthr) {
        const int i = idx / TW;
        const int x = idx - i * TW;
        const int f = x / C;
        const int o = x - f * C;
        sW_t[idx] = (f < 4) ? W[f * IN_C * C + i * C + o] : b[i * C + o];
    }
    const int n = blockIdx.x * TNPB + threadIdx.y;
    if (threadIdx.x < IN_C) sh[threadIdx.y][threadIdx.x] = h[n * IN_C + threadIdx.x];
    __syncthreads();
    const int x = threadIdx.x;
    float acc = 0.f;
#pragma unroll
    for (int i = 0; i < IN_C; ++i)
        acc = fmaf(sh[threadIdx.y][i], sW_t[i * TW + x], acc);
    T[n * TW + x] = acc;
}

// ---------- Fused layer: node-aligned edge-parallel gather + node update ----------
// Block (24,16)=384 thr owns nodes [16b,16b+16) and CSR edge range
// [off[16b], off[16b+16)). 16 y-slots stream edges cooperatively (k+=16):
// UNIFORM trip count (no divergence), independent iterations (unroll 4).
// Reduce via LDS atomicMax (order-invariant). Then 384 threads = 16x24 do the
// node update + optional next-layer T projection. Degree-0 -> 0u sentinel.
template <int IN_C, bool HAS_NEXT>
__global__ void __launch_bounds__(384)
layer3_kernel(const float* __restrict__ T_in,
              const float* __restrict__ h_in,
              const float* __restrict__ root,  // [IN_C][C]
              const float* __restrict__ bias,  // [C]
              const float* __restrict__ Wn,    // [4][C*C]
              const float* __restrict__ bn,    // [C*C]
              float* __restrict__ h_out,
              float* __restrict__ T_out) {
    __shared__ float    sWt[HAS_NEXT ? C * TW : 1];
    __shared__ float    sroot[IN_C * C];
    __shared__ float    sbias[C];
    __shared__ float    shin[LNPB][IN_C];
    __shared__ float    shh[LNPB][C];
    __shared__ unsigned sMax[LNPB][C];

    const int o = threadIdx.x;           // 0..23 channel
    const int ty = threadIdx.y;          // 0..15
    const int tid = o + C * ty;          // 0..383

    if (HAS_NEXT) {
        for (int idx = tid; idx < C * TW; idx += 384) {
            const int i = idx / TW;
            const int xx = idx - i * TW;
            const int f = xx / C;
            const int oo = xx - f * C;
            sWt[idx] = (f < 4) ? Wn[f * C * C + i * C + oo] : bn[i * C + oo];
        }
    }
    for (int idx = tid; idx < IN_C * C; idx += 384) sroot[idx] = root[idx];
    if (tid < C) sbias[tid] = bias[tid];
    sMax[ty][o] = 0u;
    const int n0 = blockIdx.x * LNPB;    // 625*16 == N_NODES exact
    if (o < IN_C) shin[ty][o] = h_in[(n0 + ty) * IN_C + o];
    __syncthreads();

    const int ks = g_off[n0];
    const int ke = g_off[n0 + LNPB];
#pragma unroll 4
    for (int k = ks + ty; k < ke; k += LNPB) {
        const int soff = g_csr_src[k];     // src*TW (broadcast across 24 lanes)
        const int d = g_csr_dst[k];
        const float4 a = g_csr_ea[k];
        const float* __restrict__ Tr = T_in + soff;
        float m = Tr[4 * C + o];
        m = fmaf(a.x, Tr[0 * C + o], m);
        m = fmaf(a.y, Tr[1 * C + o], m);
        m = fmaf(a.z, Tr[2 * C + o], m);
        m = fmaf(a.w, Tr[3 * C + o], m);
        atomicMax(&sMax[d - n0][o], fenc(m));
    }
    __syncthreads();

    // node update: thread (o, ty) owns (node n0+ty, channel o)
    const int n = n0 + ty;
    const unsigned u = sMax[ty][o];
    float r = sbias[o];
#pragma unroll
    for (int i = 0; i < IN_C; ++i) r = fmaf(shin[ty][i], sroot[i * C + o], r);
    const float h = fminf(fmaxf((u == 0u ? 0.f : fdec(u)) + r, 0.f), 6.f);
    h_out[n * C + o] = h;

    if (HAS_NEXT) {
        shh[ty][o] = h;
        __syncthreads();
#pragma unroll
        for (int f = 0; f < 5; ++f) {
            const int xx = f * C + o;
            float t = 0.f;
#pragma unroll
            for (int i = 0; i < C; ++i) t = fmaf(shh[ty][i], sWt[i * TW + xx], t);
            T_out[n * TW + xx] = t;
        }
    }
}

// ---------- Output head (deterministic two-stage GEMV) ----------
__global__ void head1_kernel(const float* __restrict__ h,
                             const float* __restrict__ w1,
                             float* __restrict__ partial) {
    __shared__ float s[256 * HID];
    const int tid = threadIdx.x;
    float acc[HID];
#pragma unroll
    for (int j = 0; j < HID; ++j) acc[j] = 0.f;
    for (int k = blockIdx.x * 256 + tid; k < N_NODES * C; k += gridDim.x * 256) {
        const float f = h[k];
        const float4* wp = (const float4*)(w1 + (size_t)k * HID);
#pragma unroll
        for (int q = 0; q < 4; ++q) {
            const float4 w = wp[q];
            acc[q * 4 + 0] = fmaf(f, w.x, acc[q * 4 + 0]);
            acc[q * 4 + 1] = fmaf(f, w.y, acc[q * 4 + 1]);
            acc[q * 4 + 2] = fmaf(f, w.z, acc[q * 4 + 2]);
            acc[q * 4 + 3] = fmaf(f, w.w, acc[q * 4 + 3]);
        }
    }
#pragma unroll
    for (int j = 0; j < HID; ++j) s[tid * HID + j] = acc[j];
    __syncthreads();
    for (int off = 128; off > 0; off >>= 1) {
        if (tid < off) {
#pragma unroll
            for (int j = 0; j < HID; ++j)
                s[tid * HID + j] += s[(tid + off) * HID + j];
        }
        __syncthreads();
    }
    if (tid < HID) partial[blockIdx.x * HID + tid] = s[tid];
}

__global__ void head2_kernel(const float* __restrict__ partial,
                             const float* __restrict__ b1,
                             const float* __restrict__ w2,
                             const float* __restrict__ b2,
                             float* __restrict__ out) {
    __shared__ float hid[HID];
    const int j = threadIdx.x;
    if (j < HID) {
        float a = b1[j];
        for (int p = 0; p < NB_HEAD; ++p) a += partial[p * HID + j];
        hid[j] = (a > 0.f) ? a : expm1f(a);
    }
    __syncthreads();
    if (j == 0) {
        float a = b2[0];
#pragma unroll
        for (int q = 0; q < HID; ++q) a += hid[q] * w2[q];
        out[0] = (a > 0.f) ? a : expm1f(a);
    }
}

extern "C" void kernel_launch(void* const* d_in, const int* in_sizes, int n_in,
                              void* d_out, int out_size, void* d_ws, size_t ws_size,
                              hipStream_t stream) {
    const float* x      = (const float*)d_in[0];
    const float* ea     = (const float*)d_in[1];
    const int*   ei     = (const int*)d_in[2];
    const float* few    = (const float*)d_in[3];
    const float* feb    = (const float*)d_in[4];
    const float* ew     = (const float*)d_in[5];
    const float* ebias  = (const float*)d_in[6];
    const float* root0  = (const float*)d_in[7];
    const float* bias0  = (const float*)d_in[8];
    const float* roots  = (const float*)d_in[9];
    const float* biases = (const float*)d_in[10];
    const float* w1     = (const float*)d_in[11];
    const float* b1     = (const float*)d_in[12];
    const float* w2     = (const float*)d_in[13];
    const float* b2     = (const float*)d_in[14];
    float* out = (float*)d_out;

    const int* src = ei;
    const int* dst = ei + N_EDGES;

    void *pTA_, *pTB_, *pA_, *pB_, *pPart_;
    hipGetSymbolAddress(&pTA_, HIP_SYMBOL(g_TA));
    hipGetSymbolAddress(&pTB_, HIP_SYMBOL(g_TB));
    hipGetSymbolAddress(&pA_,  HIP_SYMBOL(g_hA));
    hipGetSymbolAddress(&pB_,  HIP_SYMBOL(g_hB));
    hipGetSymbolAddress(&pPart_, HIP_SYMBOL(g_partial));
    float* TA = (float*)pTA_;
    float* TB = (float*)pTB_;
    float* hA = (float*)pA_;
    float* hB = (float*)pB_;
    float* partial = (float*)pPart_;

    csr_zero_kernel<<<(N_NODES + 255) / 256, 256, 0, stream>>>();
    csr_hist_kernel<<<N_EDGES / 256, 256, 0, stream>>>(dst);
    csr_scan_kernel<<<1, SCAN_T, 0, stream>>>();
    csr_scatter_kernel<<<N_EDGES / 256, 256, 0, stream>>>(src, dst, ea);

    dim3 tblk(TW, 8);
    tmat_kernel<FNODE, 8><<<N_NODES / 8, tblk, 0, stream>>>(x, few, feb, TA);

    dim3 lblk(C, LNPB);
    const int lgrid = N_NODES / LNPB;   // 625 exact
    layer3_kernel<FNODE, true><<<lgrid, lblk, 0, stream>>>(
        TA, x, root0, bias0, ew, ebias, hA, TB);
    layer3_kernel<C, true><<<lgrid, lblk, 0, stream>>>(
        TB, hA, roots + 0 * C * C, biases + 0 * C, ew, ebias, hB, TA);
    layer3_kernel<C, true><<<lgrid, lblk, 0, stream>>>(
        TA, hB, roots + 1 * C * C, biases + 1 * C, ew, ebias, hA, TB);
    layer3_kernel<C, true><<<lgrid, lblk, 0, stream>>>(
        TB, hA, roots + 2 * C * C, biases + 2 * C, ew, ebias, hB, TA);
    layer3_kernel<C, false><<<lgrid, lblk, 0, stream>>>(
        TA, hB, roots + 3 * C * C, biases + 3 * C, ew, ebias, hA, TB);

    head1_kernel<<<NB_HEAD, 256, 0, stream>>>(hA, w1, partial);
    head2_kernel<<<1, 64, 0, stream>>>(partial, b1, w2, b2, out);
}